// Round 13
// baseline (629.050 us; speedup 1.0000x reference)
//
#include <hip/hip_runtime.h>
#include <hip/hip_bf16.h>
#include <stdint.h>

// ---------------------------------------------------------------------------
// QuantGRU: T=512, B=64, I=256, H=256. ACT scale 2^-7, W scale 2^-8.
// Fully exact integer arithmetic; sigmoid/tanh via 256-entry f64-built LUTs.
// R13: 768 thr/block (12 waves, 3/SIMD => 170-VGPR budget). Thread j owns ONE
// R column (64 weight dwords) -- small enough to be register-resident -- and
// an asm volatile "+v" touch INSIDE the t-loop forces the allocator to keep
// them live (R5-R12 showed it otherwise re-loads 192KB/step from L1/L2, the
// ~800-1900 cyc/step wall all previous variants sat at).
// GEMV: h broadcast via 1 ds_read_b32 + 64 readlane->SGPR; dot4 vs resident
// weights. v -> LDS int8; gates on threads 0-255; 2 light barriers/step.
// ---------------------------------------------------------------------------

#define T_STEPS 512
#define BATCH   64
#define IDIM    256
#define HDIM    256
#define N3H     768   // 3*H

#if defined(__has_builtin)
#if __has_builtin(__builtin_amdgcn_sdot4)
#define DOT4(a,b,c) __builtin_amdgcn_sdot4((int)(a),(int)(b),(int)(c),false)
#endif
#endif
#ifndef DOT4
__device__ __forceinline__ int dot4_sw(uint32_t a, uint32_t b, int c){
  c += (int)(int8_t)(a)      * (int)(int8_t)(b);
  c += (int)(int8_t)(a>>8)   * (int)(int8_t)(b>>8);
  c += (int)(int8_t)(a>>16)  * (int)(int8_t)(b>>16);
  c += (int)(int8_t)(a>>24)  * (int)(int8_t)(b>>24);
  return c;
}
#define DOT4(a,b,c) dot4_sw((uint32_t)(a),(uint32_t)(b),(int)(c))
#endif

// select dword component of a uint4 by compile-time constant
#define CHUNK(W,c) (((c)&3)==0 ? W[(c)>>2].x : ((c)&3)==1 ? W[(c)>>2].y : \
                    ((c)&3)==2 ? W[(c)>>2].z : W[(c)>>2].w)

// LDS-only workgroup barrier (no vmcnt drain; loads/stores stay in flight)
__device__ __forceinline__ void barrier_lds() {
  asm volatile("s_waitcnt lgkmcnt(0)\n\ts_barrier" ::: "memory");
}

// ---- exact integer round-to-nearest-even helpers (verified vs jnp.round) ---
__device__ __forceinline__ int clamp8(int x)   { return min(127, max(-128, x)); }
__device__ __forceinline__ int rne_half(int y) { int t = y >> 1; return t + (t & y & 1); }
__device__ __forceinline__ int rne_s8(int s)   { return (s + 127 + ((s >> 8) & 1)) >> 8; }
__device__ __forceinline__ int rne_s7(int p)   { return (p + 63 + ((p >> 7) & 1)) >> 7; }

// float RNE+clamp (quantize; used in prep/gemm only)
__device__ __forceinline__ int rneclamp(float v) {
  int q = (int)rintf(v);
  return min(127, max(-128, q));
}

__device__ __forceinline__ uint32_t packq4(float4 f, float sc) {
  uint32_t b0 = (uint32_t)(uint8_t)(int8_t)rneclamp(f.x * sc);
  uint32_t b1 = (uint32_t)(uint8_t)(int8_t)rneclamp(f.y * sc);
  uint32_t b2 = (uint32_t)(uint8_t)(int8_t)rneclamp(f.z * sc);
  uint32_t b3 = (uint32_t)(uint8_t)(int8_t)rneclamp(f.w * sc);
  return b0 | (b1 << 8) | (b2 << 16) | (b3 << 24);
}

// ---------------------------------------------------------------------------
// prep: W AND R -> k-chunk-transposed int8: uint4 #kk of column j sits at
// ((uint4*)X)[kk*768 + j]  => consecutive j = fully coalesced wave loads.
// ---------------------------------------------------------------------------
__global__ void prep_kernel(const float* __restrict__ W, const float* __restrict__ R,
                            const float* __restrict__ bx, const float* __restrict__ br,
                            int8_t* __restrict__ Wq, int8_t* __restrict__ Rq,
                            int8_t* __restrict__ bx8, int8_t* __restrict__ br8) {
  const int NW = IDIM * N3H; // 196608
  int idx = blockIdx.x * 256 + threadIdx.x;
  if (idx < NW) {
    int k = idx / N3H, j = idx % N3H;
    Wq[((size_t)(k >> 4) * N3H + j) * 16 + (k & 15)] = (int8_t)rneclamp(W[idx] * 256.0f);
  } else if (idx < 2 * NW) {
    int i2 = idx - NW;
    int k = i2 / N3H, j = i2 % N3H;
    Rq[((size_t)(k >> 4) * N3H + j) * 16 + (k & 15)] = (int8_t)rneclamp(R[i2] * 256.0f);
  } else if (idx < 2 * NW + N3H) {
    int i2 = idx - 2 * NW;
    bx8[i2] = (int8_t)rneclamp(bx[i2] * 256.0f);
  } else if (idx < 2 * NW + 2 * N3H) {
    int i2 = idx - 2 * NW - N3H;
    br8[i2] = (int8_t)rneclamp(br[i2] * 256.0f);
  }
}

// ---------------------------------------------------------------------------
// gemm_wx: Wx_q[b][t][j] = clamp(rne( (fq(x) . Wq col j) / 256 ))  (int8)
// one block per t (64 rows), 768 threads = one per output column.
// ---------------------------------------------------------------------------
__global__ __launch_bounds__(768, 1) void gemm_wx_kernel(
    const float* __restrict__ x, const int8_t* __restrict__ Wq,
    int8_t* __restrict__ WxQ8) {
  const int t = blockIdx.x;   // 0..511
  const int j = threadIdx.x;  // 0..767

  __shared__ uint4 xq4[64 * 16];   // 64 rows x 256 int8 = 16KB
  uint32_t* xq = (uint32_t*)xq4;

  uint4 w[16];
  const uint4* wp = (const uint4*)Wq;
  #pragma unroll
  for (int kk = 0; kk < 16; ++kk) w[kk] = wp[kk * N3H + j];

  const float4* xg = (const float4*)(x) + (size_t)t * 4096;
  for (int i = j; i < 4096; i += 768) {
    float4 f = xg[i];
    xq[i] = packq4(f, 128.0f);
  }
  __syncthreads();

  for (int r = 0; r < 64; ++r) {
    int s = 0;
    #pragma unroll
    for (int kk = 0; kk < 16; ++kk) {
      uint4 hv = xq4[r * 16 + kk];
      s = DOT4(hv.x, w[kk].x, s);
      s = DOT4(hv.y, w[kk].y, s);
      s = DOT4(hv.z, w[kk].z, s);
      s = DOT4(hv.w, w[kk].w, s);
    }
    int q = clamp8(rne_s8(s));
    WxQ8[((size_t)r * T_STEPS + t) * N3H + j] = (int8_t)q;
  }
}

// ---------------------------------------------------------------------------
// gru_rec13: one block per batch; 768 threads (12 waves, 3/SIMD).
// Thread j: GEMV for column j vs register-resident 64-dword weight column.
// Threads 0-255 additionally run the exact-integer gate tail for h[j].
// ---------------------------------------------------------------------------
__global__ __launch_bounds__(768, 3)
void gru_rec13_kernel(
    const float* __restrict__ h0, const int8_t* __restrict__ Rq,
    const int8_t* __restrict__ bx8, const int8_t* __restrict__ br8,
    const int8_t* __restrict__ WxQ8, float* __restrict__ out) {
  const int b = blockIdx.x;     // batch element
  const int j = threadIdx.x;    // 0..767 (column)
  const int lane = j & 63;

  __shared__ uint32_t hq[2][64];    // double-buffered int8 h (256 B each)
  __shared__ int8_t vbuf[N3H];      // v values (int8), published per step
  __shared__ int8_t lutS[256];
  __shared__ int8_t lutT[256];

  // weight column j: 16 uint4 = 64 dwords, coalesced from transposed layout
  uint4 w[16];
  {
    const uint4* rp = (const uint4*)Rq;
    #pragma unroll
    for (int kk = 0; kk < 16; ++kk) w[kk] = rp[kk * N3H + j];
  }
  const int vb = (int)br8[j];       // recurrent bias for own column

  // gate-thread state (j < 256)
  int hi = 0, bzc = 0, brc = 0, bgc = 0;
  const int8_t* wxp = WxQ8 + (size_t)b * T_STEPS * N3H + j;
  int wxA0 = 0, wxA1 = 0, wxA2 = 0, wxB0 = 0, wxB1 = 0, wxB2 = 0;
  if (j < 256) {
    double a = ((double)j - 128.0) / 128.0;
    lutS[j] = (int8_t)min(127, max(-128, (int)rint(128.0 / (1.0 + exp(-a)))));
    lutT[j] = (int8_t)min(127, max(-128, (int)rint(128.0 * tanh(a))));
    bzc = (int)bx8[j];
    brc = (int)bx8[j + 256];
    bgc = (int)bx8[j + 512];
    hi = (int)rintf(h0[b * HDIM + j] * 128.0f);   // exact int, units 1/128
    ((int8_t*)&hq[0][0])[j] = (int8_t)clamp8(hi);
    // 2-deep Wx prefetch
    wxA0 = (int)wxp[0];   wxA1 = (int)wxp[256];       wxA2 = (int)wxp[512];
    wxB0 = (int)wxp[N3H]; wxB1 = (int)wxp[N3H + 256]; wxB2 = (int)wxp[N3H + 512];
  }
  __syncthreads();

  float* outp = out + (size_t)b * HDIM + (j < 256 ? j : 0);

  for (int t = 0; t < T_STEPS; ++t) {
    const int cur = t & 1, nxt = cur ^ 1;

    // FORCE weight residency: asm "may modify" w every iteration =>
    // rematerialization from memory is illegal, values stay in VGPRs.
    #pragma unroll
    for (int kk = 0; kk < 16; ++kk)
      asm volatile("" : "+v"(w[kk].x), "+v"(w[kk].y), "+v"(w[kk].z), "+v"(w[kk].w));

    // issue Wx loads for t+2 (gate threads; ~2 steps of latency hiding)
    int nz = 0, nr = 0, ng = 0;
    if (j < 256) {
      const int8_t* p = wxp + (size_t)min(t + 2, T_STEPS - 1) * N3H;
      nz = (int)p[0]; nr = (int)p[256]; ng = (int)p[512];
    }

    // ---- GEMV: h via lane-strided ds_read_b32 + readlane -> SGPR ----
    uint32_t hw = hq[cur][lane];
    int s0 = 0, s1 = 0;
    #pragma unroll
    for (int c = 0; c < 64; c += 2) {
      int h0c = __builtin_amdgcn_readlane((int)hw, c);
      int h1c = __builtin_amdgcn_readlane((int)hw, c + 1);
      s0 = DOT4(h0c, CHUNK(w, c), s0);
      s1 = DOT4(h1c, CHUNK(w, c + 1), s1);
    }
    int s = s0 + s1;
    // v = fq(fq(s/2^15,7)+br,7)  -- all integer, exact
    int v = clamp8(rne_half(2 * clamp8(rne_s8(s)) + vb));
    vbuf[j] = (int8_t)v;
    barrier_lds();   // #1: vbuf ready

    // ---- gate tail (threads 0-255), exact integer ----
    if (j < 256) {
      int vz = (int)vbuf[j], vr = (int)vbuf[j + 256], vg = (int)vbuf[j + 512];
      int az = clamp8(rne_half(2 * (wxA0 + vz) + bzc));
      int zi = (int)lutS[az + 128];
      int ar = clamp8(rne_half(2 * (wxA1 + vr) + brc));
      int ri = (int)lutS[ar + 128];
      int rrh = clamp8(rne_s7(ri * vg));
      int ag = clamp8(rne_half(2 * (wxA2 + rrh) + bgc));
      int gi = (int)lutT[ag + 128];
      int oldi = clamp8(rne_s7(zi * hi));
      int newi = clamp8(rne_s7((128 - zi) * gi));
      hi = oldi + newi;                       // integer, units 1/128
      outp[(size_t)t * BATCH * HDIM] = (float)hi * (1.0f / 128.0f);
      ((int8_t*)&hq[nxt][0])[j] = (int8_t)clamp8(hi);
      // advance Wx pipeline
      wxA0 = wxB0; wxA1 = wxB1; wxA2 = wxB2;
      wxB0 = nz;   wxB1 = nr;   wxB2 = ng;
    }
    barrier_lds();   // #2: hq[nxt] published
  }
}

// ---------------------------------------------------------------------------
extern "C" void kernel_launch(void* const* d_in, const int* in_sizes, int n_in,
                              void* d_out, int out_size, void* d_ws, size_t ws_size,
                              hipStream_t stream) {
  const float* x  = (const float*)d_in[0];   // (T,B,I)
  const float* h0 = (const float*)d_in[1];   // (B,H)
  const float* W  = (const float*)d_in[2];   // (I,3H)
  const float* R  = (const float*)d_in[3];   // (H,3H)
  const float* bx = (const float*)d_in[4];   // (3H,)
  const float* br = (const float*)d_in[5];   // (3H,)
  float* out = (float*)d_out;                // (T,B,H)

  // workspace layout
  const size_t NW = (size_t)IDIM * N3H;          // 196608
  int8_t* Wq  = (int8_t*)d_ws;                   // 196608
  int8_t* Rq  = Wq + NW;                         // 196608
  int8_t* bx8 = Rq + NW;                         // 768
  int8_t* br8 = bx8 + N3H;                       // 768
  int8_t* WxQ8 = br8 + N3H;                      // 64*512*768 = 25165824

  {
    int total = (int)(2 * NW + 2 * N3H);
    int blocks = (total + 255) / 256;
    prep_kernel<<<blocks, 256, 0, stream>>>(W, R, bx, br, Wq, Rq, bx8, br8);
  }
  gemm_wx_kernel<<<T_STEPS, 768, 0, stream>>>(x, Wq, WxQ8);
  gru_rec13_kernel<<<BATCH, 768, 0, stream>>>(h0, Rq, bx8, br8, WxQ8, out);
}

// Round 14
// 495.356 us; speedup vs baseline: 1.2699x; 1.2699x over previous
//
#include <hip/hip_runtime.h>
#include <hip/hip_bf16.h>
#include <stdint.h>

// ---------------------------------------------------------------------------
// QuantGRU: T=512, B=64, I=256, H=256. ACT scale 2^-7, W scale 2^-8.
// Fully exact integer arithmetic; sigmoid/tanh via 256-entry f64-built LUTs.
// R14: recurrence GEMV via MFMA i8 (the only MAC that reads AGPR-parked
// operands natively -- v_dot4 cannot, which forced ~192 shuttle ops/step in
// all previous designs). Per step: S(16x768) = A(16x256)*B(256x768), only
// M-row 0 real (1 batch/block, garbage rows harmless). B fragments packed by
// prep in exact lane order; A built from hq row via 4 broadcast ds_read_b128.
// Row-0 extracted per verified C layout (col=lane&15, row=(lane>>4)*4+reg).
// Gate tail = proven exact-integer R6 code reading S from LDS.
// ---------------------------------------------------------------------------

#define T_STEPS 512
#define BATCH   64
#define IDIM    256
#define HDIM    256
#define N3H     768   // 3*H

typedef int v4i __attribute__((ext_vector_type(4)));

#if defined(__has_builtin)
#if __has_builtin(__builtin_amdgcn_sdot4)
#define DOT4(a,b,c) __builtin_amdgcn_sdot4((int)(a),(int)(b),(int)(c),false)
#endif
#endif
#ifndef DOT4
__device__ __forceinline__ int dot4_sw(uint32_t a, uint32_t b, int c){
  c += (int)(int8_t)(a)      * (int)(int8_t)(b);
  c += (int)(int8_t)(a>>8)   * (int)(int8_t)(b>>8);
  c += (int)(int8_t)(a>>16)  * (int)(int8_t)(b>>16);
  c += (int)(int8_t)(a>>24)  * (int)(int8_t)(b>>24);
  return c;
}
#define DOT4(a,b,c) dot4_sw((uint32_t)(a),(uint32_t)(b),(int)(c))
#endif

// LDS-only workgroup barrier (no vmcnt drain; loads/stores stay in flight)
__device__ __forceinline__ void barrier_lds() {
  asm volatile("s_waitcnt lgkmcnt(0)\n\ts_barrier" ::: "memory");
}

// ---- exact integer round-to-nearest-even helpers (verified vs jnp.round) ---
__device__ __forceinline__ int clamp8(int x)   { return min(127, max(-128, x)); }
__device__ __forceinline__ int rne_half(int y) { int t = y >> 1; return t + (t & y & 1); }
__device__ __forceinline__ int rne_s8(int s)   { return (s + 127 + ((s >> 8) & 1)) >> 8; }
__device__ __forceinline__ int rne_s7(int p)   { return (p + 63 + ((p >> 7) & 1)) >> 7; }

// float RNE+clamp (quantize; used in prep/gemm only)
__device__ __forceinline__ int rneclamp(float v) {
  int q = (int)rintf(v);
  return min(127, max(-128, q));
}

__device__ __forceinline__ uint32_t packq4(float4 f, float sc) {
  uint32_t b0 = (uint32_t)(uint8_t)(int8_t)rneclamp(f.x * sc);
  uint32_t b1 = (uint32_t)(uint8_t)(int8_t)rneclamp(f.y * sc);
  uint32_t b2 = (uint32_t)(uint8_t)(int8_t)rneclamp(f.z * sc);
  uint32_t b3 = (uint32_t)(uint8_t)(int8_t)rneclamp(f.w * sc);
  return b0 | (b1 << 8) | (b2 << 16) | (b3 << 24);
}

// ---------------------------------------------------------------------------
// prep: W -> k-chunk-transposed int8 (for gemm_wx), R -> MFMA B-FRAGMENT
// layout: byte (((n*4+s)*64+l)*16+e) = Rq[k][col], k=s*64+(l>>4)*16+e,
// col=n*16+(l&15)  (n=N-tile 0..47, s=K-slice 0..3, l=lane, e=byte).
// ---------------------------------------------------------------------------
__global__ void prep_kernel(const float* __restrict__ W, const float* __restrict__ R,
                            const float* __restrict__ bx, const float* __restrict__ br,
                            int8_t* __restrict__ Wq, int8_t* __restrict__ BF,
                            int8_t* __restrict__ bx8, int8_t* __restrict__ br8) {
  const int NW = IDIM * N3H; // 196608
  int idx = blockIdx.x * 256 + threadIdx.x;
  if (idx < NW) {
    int k = idx / N3H, j = idx % N3H;
    Wq[((size_t)(k >> 4) * N3H + j) * 16 + (k & 15)] = (int8_t)rneclamp(W[idx] * 256.0f);
  } else if (idx < 2 * NW) {
    int i2 = idx - NW;               // linear index into BF
    int e = i2 & 15;
    int l = (i2 >> 4) & 63;
    int s = (i2 >> 10) & 3;
    int n = i2 >> 12;                // 0..47
    int k   = s * 64 + ((l >> 4) << 4) + e;
    int col = n * 16 + (l & 15);
    BF[i2] = (int8_t)rneclamp(R[(size_t)k * N3H + col] * 256.0f);
  } else if (idx < 2 * NW + N3H) {
    int i2 = idx - 2 * NW;
    bx8[i2] = (int8_t)rneclamp(bx[i2] * 256.0f);
  } else if (idx < 2 * NW + 2 * N3H) {
    int i2 = idx - 2 * NW - N3H;
    br8[i2] = (int8_t)rneclamp(br[i2] * 256.0f);
  }
}

// ---------------------------------------------------------------------------
// gemm_wx: Wx_q[b][t][j] = clamp(rne( (fq(x) . Wq col j) / 256 ))  (int8)
// one block per t (64 rows), 768 threads = one per output column.
// ---------------------------------------------------------------------------
__global__ __launch_bounds__(768, 1) void gemm_wx_kernel(
    const float* __restrict__ x, const int8_t* __restrict__ Wq,
    int8_t* __restrict__ WxQ8) {
  const int t = blockIdx.x;   // 0..511
  const int j = threadIdx.x;  // 0..767

  __shared__ uint4 xq4[64 * 16];   // 64 rows x 256 int8 = 16KB
  uint32_t* xq = (uint32_t*)xq4;

  uint4 w[16];
  const uint4* wp = (const uint4*)Wq;
  #pragma unroll
  for (int kk = 0; kk < 16; ++kk) w[kk] = wp[kk * N3H + j];

  const float4* xg = (const float4*)(x) + (size_t)t * 4096;
  for (int i = j; i < 4096; i += 768) {
    float4 f = xg[i];
    xq[i] = packq4(f, 128.0f);
  }
  __syncthreads();

  for (int r = 0; r < 64; ++r) {
    int s = 0;
    #pragma unroll
    for (int kk = 0; kk < 16; ++kk) {
      uint4 hv = xq4[r * 16 + kk];
      s = DOT4(hv.x, w[kk].x, s);
      s = DOT4(hv.y, w[kk].y, s);
      s = DOT4(hv.z, w[kk].z, s);
      s = DOT4(hv.w, w[kk].w, s);
    }
    int q = clamp8(rne_s8(s));
    WxQ8[((size_t)r * T_STEPS + t) * N3H + j] = (int8_t)q;
  }
}

// ---------------------------------------------------------------------------
// gru_rec14: one block per batch; 512 threads = 8 waves.
// All waves: MFMA S = hq @ R (6 N-tiles each). Waves 0-3: exact gate tail.
// ---------------------------------------------------------------------------
__global__ __launch_bounds__(512, 1)
void gru_rec14_kernel(
    const float* __restrict__ h0, const int8_t* __restrict__ BF,
    const int8_t* __restrict__ bx8, const int8_t* __restrict__ br8,
    const int8_t* __restrict__ WxQ8, float* __restrict__ out) {
  const int b    = blockIdx.x;      // batch element
  const int tid  = threadIdx.x;     // 0..511
  const int lane = tid & 63;
  const int wave = tid >> 6;        // 0..7
  const int j    = tid & 255;       // gate index (tid<256)

  __shared__ alignas(16) int8_t hq[2][256];   // int8 h (row 0 of A)
  __shared__ int    Sbuf[N3H];                // raw i32 GEMV results
  __shared__ int8_t lutS[256];
  __shared__ int8_t lutT[256];

  // B fragments: 6 N-tiles x 4 K-slices, packed by prep in lane order
  v4i bf[6][4];
  {
    const v4i* bp = (const v4i*)BF;
    #pragma unroll
    for (int i = 0; i < 6; ++i)
      #pragma unroll
      for (int s = 0; s < 4; ++s)
        bf[i][s] = bp[((wave * 6 + i) * 4 + s) * 64 + lane];
  }

  // gate-thread state (tid < 256)
  int hi = 0, bzc = 0, brc = 0, bgc = 0, vbz = 0, vbr = 0, vbg = 0;
  const int8_t* wxp = WxQ8 + (size_t)b * T_STEPS * N3H + j;
  int wxA0 = 0, wxA1 = 0, wxA2 = 0, wxB0 = 0, wxB1 = 0, wxB2 = 0;
  if (tid < 256) {
    double a = ((double)j - 128.0) / 128.0;
    lutS[j] = (int8_t)min(127, max(-128, (int)rint(128.0 / (1.0 + exp(-a)))));
    lutT[j] = (int8_t)min(127, max(-128, (int)rint(128.0 * tanh(a))));
    bzc = (int)bx8[j];
    brc = (int)bx8[j + 256];
    bgc = (int)bx8[j + 512];
    vbz = (int)br8[j];
    vbr = (int)br8[j + 256];
    vbg = (int)br8[j + 512];
    hi = (int)rintf(h0[b * HDIM + j] * 128.0f);   // exact int, units 1/128
    hq[0][j] = (int8_t)clamp8(hi);
    wxA0 = (int)wxp[0];   wxA1 = (int)wxp[256];       wxA2 = (int)wxp[512];
    wxB0 = (int)wxp[N3H]; wxB1 = (int)wxp[N3H + 256]; wxB2 = (int)wxp[N3H + 512];
  }
  __syncthreads();

  float* outp = out + (size_t)b * HDIM + j;
  const int kg = (lane >> 4) << 4;   // 0,16,32,48 within each 64-wide K-slice

  for (int t = 0; t < T_STEPS; ++t) {
    const int cur = t & 1, nxt = cur ^ 1;

    // issue Wx loads for t+2 (gate threads)
    int nz = 0, nr = 0, ng = 0;
    if (tid < 256) {
      const int8_t* p = wxp + (size_t)min(t + 2, T_STEPS - 1) * N3H;
      nz = (int)p[0]; nr = (int)p[256]; ng = (int)p[512];
    }

    // ---- A fragments from hq row (rows 1-15 of A are duplicates; harmless)
    v4i a0 = *(const v4i*)&hq[cur][  0 + kg];
    v4i a1 = *(const v4i*)&hq[cur][ 64 + kg];
    v4i a2 = *(const v4i*)&hq[cur][128 + kg];
    v4i a3 = *(const v4i*)&hq[cur][192 + kg];

    // ---- MFMA: 6 tiles x 4 K-slices
    v4i acc[6];
    #pragma unroll
    for (int i = 0; i < 6; ++i) {
      v4i z = {0, 0, 0, 0};
      z = __builtin_amdgcn_mfma_i32_16x16x64_i8(a0, bf[i][0], z, 0, 0, 0);
      z = __builtin_amdgcn_mfma_i32_16x16x64_i8(a1, bf[i][1], z, 0, 0, 0);
      z = __builtin_amdgcn_mfma_i32_16x16x64_i8(a2, bf[i][2], z, 0, 0, 0);
      z = __builtin_amdgcn_mfma_i32_16x16x64_i8(a3, bf[i][3], z, 0, 0, 0);
      acc[i] = z;
    }
    // ---- extract row 0: col=lane&15, row=(lane>>4)*4+reg => lanes 0-15, reg 0
    if (lane < 16) {
      #pragma unroll
      for (int i = 0; i < 6; ++i)
        Sbuf[(wave * 6 + i) * 16 + lane] = acc[i][0];
    }
    barrier_lds();   // #1: Sbuf ready

    // ---- gate tail (threads 0-255), exact integer (verbatim R6) ----
    if (tid < 256) {
      int sz = Sbuf[j], sr = Sbuf[j + 256], sg = Sbuf[j + 512];
      int vz = clamp8(rne_half(2 * clamp8(rne_s8(sz)) + vbz));
      int vr = clamp8(rne_half(2 * clamp8(rne_s8(sr)) + vbr));
      int vg = clamp8(rne_half(2 * clamp8(rne_s8(sg)) + vbg));
      int az = clamp8(rne_half(2 * (wxA0 + vz) + bzc));
      int zi = (int)lutS[az + 128];
      int ar = clamp8(rne_half(2 * (wxA1 + vr) + brc));
      int ri = (int)lutS[ar + 128];
      int rrh = clamp8(rne_s7(ri * vg));
      int ag = clamp8(rne_half(2 * (wxA2 + rrh) + bgc));
      int gi = (int)lutT[ag + 128];
      int oldi = clamp8(rne_s7(zi * hi));
      int newi = clamp8(rne_s7((128 - zi) * gi));
      hi = oldi + newi;                       // integer, units 1/128
      outp[(size_t)t * BATCH * HDIM] = (float)hi * (1.0f / 128.0f);
      hq[nxt][j] = (int8_t)clamp8(hi);
      wxA0 = wxB0; wxA1 = wxB1; wxA2 = wxB2;
      wxB0 = nz;   wxB1 = nr;   wxB2 = ng;
    }
    barrier_lds();   // #2: hq[nxt] published
  }
}

// ---------------------------------------------------------------------------
extern "C" void kernel_launch(void* const* d_in, const int* in_sizes, int n_in,
                              void* d_out, int out_size, void* d_ws, size_t ws_size,
                              hipStream_t stream) {
  const float* x  = (const float*)d_in[0];   // (T,B,I)
  const float* h0 = (const float*)d_in[1];   // (B,H)
  const float* W  = (const float*)d_in[2];   // (I,3H)
  const float* R  = (const float*)d_in[3];   // (H,3H)
  const float* bx = (const float*)d_in[4];   // (3H,)
  const float* br = (const float*)d_in[5];   // (3H,)
  float* out = (float*)d_out;                // (T,B,H)

  // workspace layout
  const size_t NW = (size_t)IDIM * N3H;          // 196608
  int8_t* Wq  = (int8_t*)d_ws;                   // 196608
  int8_t* BF  = Wq + NW;                         // 196608 (R as MFMA B-frags)
  int8_t* bx8 = BF + NW;                         // 768
  int8_t* br8 = bx8 + N3H;                       // 768
  int8_t* WxQ8 = br8 + N3H;                      // 64*512*768 = 25165824

  {
    int total = (int)(2 * NW + 2 * N3H);
    int blocks = (total + 255) / 256;
    prep_kernel<<<blocks, 256, 0, stream>>>(W, R, bx, br, Wq, BF, bx8, br8);
  }
  gemm_wx_kernel<<<T_STEPS, 768, 0, stream>>>(x, Wq, WxQ8);
  gru_rec14_kernel<<<BATCH, 512, 0, stream>>>(h0, BF, bx8, br8, WxQ8, out);
}